// Round 1
// baseline (248.344 us; speedup 1.0000x reference)
//
#include <hip/hip_runtime.h>

// Axial 7x7 attention, fused. Shapes fixed: N=512, GRID=7, Cq=64, Cv=512, B=3584.
// Redesign vs previous version:
//  - grid 1024: block = (n, c-half of 256); 30KB LDS + 64 VGPR -> 4 blocks/CU (100% occ ceiling)
//  - k and v stored TRANSPOSED in LDS as [a][j][c] (c contiguous, strides 68/484 -> <=2-way banks)
//  - q read straight from global (L1-broadcast rows), no q/k double staging
//  - staging: wave-uniform (arr,w,j), lane-contiguous c -> strided global dword + linear ds_write
//  - T14 split: next-chunk v loads issued into regs before computing current chunk

#define NEGINF (-1e20f)

constexpr int QK_SLICE = 7 * 7 * 64;    // 3136 floats per n for q/k arrays
constexpr int V_SLICE  = 7 * 512 * 7;   // 25088 floats per n for v arrays / out

// decode staging element: q6 in 0..97 -> (arr, w, j); wj<49 so (wj*37)>>8 == wj/7
#define DECODE(q6v, arr, wj, w, j)        \
    const int arr = (q6v) >= 49;          \
    const int wj  = (q6v) - 49 * arr;     \
    const int w   = (wj * 37) >> 8;       \
    const int j   = wj - 7 * w;

__global__ __launch_bounds__(512, 8) void fused_axial(
    const float* __restrict__ qH, const float* __restrict__ kH,
    const float* __restrict__ vH, const float* __restrict__ qW,
    const float* __restrict__ kW, const float* __restrict__ vW,
    float* __restrict__ out)
{
    // LDS: As/Bs: [7][7][68], a-stride 484 (=7*68+8) -> 3388 floats each
    //      P: 49 rows, stride 17 -> 833 floats.  total 7609 floats = 30436 B
    __shared__ float sm[7609];
    float* As = sm;
    float* Bs = sm + 3388;
    float* P  = sm + 6776;

    const int bid  = blockIdx.x;
    const int work = (bid & 7) * 128 + (bid >> 3);   // XCD-contiguous, bijective (1024 % 8 == 0)
    const int n    = work >> 1;
    const int hf   = work & 1;                        // c-half: 0 -> c 0..255, 1 -> 256..511
    const int t    = threadIdx.x;

    const float* qHn = qH + n * QK_SLICE;
    const float* kHn = kH + n * QK_SLICE;
    const float* qWn = qW + n * QK_SLICE;
    const float* kWn = kW + n * QK_SLICE;
    const float* vHn = vH + n * V_SLICE;
    const float* vWn = vW + n * V_SLICE;
    float* outn = out + n * V_SLICE;

    const int c   = t & 63;     // lane-contiguous channel within a staged row
    const int q6b = t >> 6;     // wave id 0..7 (wave-uniform)

    // ---- Phase K: stage kT[a][j][c] for both arrays (6272 elems, 13 per thread) ----
    {
        float r[13];
        #pragma unroll
        for (int u = 0; u < 13; ++u) {
            const int q6 = q6b + 8 * u;
            if (u < 12 || q6 < 98) {
                DECODE(q6, arr, wj, w, j)
                r[u] = *((arr ? kWn : kHn) + w * 448 + c * 7 + j);
            }
        }
        #pragma unroll
        for (int u = 0; u < 13; ++u) {
            const int q6 = q6b + 8 * u;
            if (u < 12 || q6 < 98) {
                DECODE(q6, arr, wj, w, j)
                (arr ? Bs : As)[w * 484 + j * 68 + c] = r[u];
            }
        }
    }

    // ---- prefetch v chunk 0 into regs (lands during logits/softmax) ----
    float vr[13];
    {
        const int c7 = (hf * 256 + c) * 7;
        #pragma unroll
        for (int u = 0; u < 13; ++u) {
            const int q6 = q6b + 8 * u;
            if (u < 12 || q6 < 98) {
                DECODE(q6, arr, wj, w, j)
                vr[u] = *((arr ? vWn : vHn) + w * 3584 + c7 + j);
            }
        }
    }
    __syncthreads();   // kT staged

    // ---- Phase L: 686 logits; q rows from global (L1-broadcast), kT from LDS ----
    {
        auto do_dot = [&](int d) {
            const bool isH = d < 343;
            const int dd  = isH ? d : d - 343;
            const int a   = (dd * 1339) >> 16;    // dd/49 (valid dd<512)
            const int rem = dd - a * 49;
            const int b   = (rem * 37) >> 8;      // rem/7
            const int j   = rem - 7 * b;
            // H: a=w, b=h, j=j   W: a=h, b=w, j=y
            const float* qrow = (isH ? qHn : qWn) + (a * 7 + b) * 64;
            const float* krow = (isH ? As : Bs) + a * 484 + j * 68;
            float e = 0.f;
            #pragma unroll
            for (int cc = 0; cc < 64; cc += 4) {
                float4 qv = *(const float4*)(qrow + cc);
                float4 kv = *(const float4*)(krow + cc);
                e += qv.x * kv.x + qv.y * kv.y + qv.z * kv.z + qv.w * kv.w;
            }
            if (isH) {
                if (b == j) e = NEGINF;           // diagonal mask on eH (h==j)
                P[(b * 7 + a) * 17 + j] = e;      // logits[n,h,w,j]
            } else {
                P[(a * 7 + b) * 17 + 7 + j] = e;  // logits[n,h,w,7+y]
            }
        };
        do_dot(t);
        if (t < 174) do_dot(512 + t);
    }
    __syncthreads();

    // ---- Phase S: softmax over 14 per (h,w) ----
    if (t < 49) {
        float* row = P + t * 17;
        float l[14];
        float m = -3.4e38f;
        #pragma unroll
        for (int k = 0; k < 14; ++k) { l[k] = row[k]; m = fmaxf(m, l[k]); }
        float s = 0.f;
        #pragma unroll
        for (int k = 0; k < 14; ++k) { l[k] = __expf(l[k] - m); s += l[k]; }
        float inv = 1.f / s;
        #pragma unroll
        for (int k = 0; k < 14; ++k) row[k] = l[k] * inv;
    }
    __syncthreads();

    // ---- Phase PV: thread -> (g, hw); 4 chunks of 64 c per half ----
    const int g  = (t * 1339) >> 16;     // t/49
    const int hw = t - g * 49;
    const int h  = (hw * 37) >> 8;
    const int w  = hw - 7 * h;
    const bool active = (t < 490);

    float pr[14];
    if (active) {
        #pragma unroll
        for (int k = 0; k < 14; ++k) pr[k] = P[hw * 17 + k];
    }

    for (int chunk = 0; chunk < 4; ++chunk) {
        // As/Bs are free here (logits done / previous compute done).
        // Write staged regs (waits on chunk's global loads), then issue next chunk's loads.
        #pragma unroll
        for (int u = 0; u < 13; ++u) {
            const int q6 = q6b + 8 * u;
            if (u < 12 || q6 < 98) {
                DECODE(q6, arr, wj, w2, j2)
                (arr ? Bs : As)[w2 * 484 + j2 * 68 + c] = vr[u];
            }
        }
        if (chunk < 3) {
            const int c7n = (hf * 256 + (chunk + 1) * 64 + c) * 7;
            #pragma unroll
            for (int u = 0; u < 13; ++u) {
                const int q6 = q6b + 8 * u;
                if (u < 12 || q6 < 98) {
                    DECODE(q6, arr, wj, w2, j2)
                    vr[u] = *((arr ? vWn : vHn) + w2 * 3584 + c7n + j2);
                }
            }
        }
        __syncthreads();   // staging visible

        if (active) {
            const int c0 = hf * 256 + chunk * 64;
            const float* arow = As + w * 484;   // vH: indexed by thread's w
            const float* brow = Bs + h * 484;   // vW: indexed by thread's h
            #pragma unroll
            for (int it = 0; it < 2; ++it) {
                if (it == 0 || g < 6) {
                    const int cl4 = (g + 10 * it) * 4;   // 16 quads of 4 channels
                    float4 acc = make_float4(0.f, 0.f, 0.f, 0.f);
                    #pragma unroll
                    for (int j2 = 0; j2 < 7; ++j2) {
                        float4 av = *(const float4*)(arow + j2 * 68 + cl4);
                        acc.x += pr[j2] * av.x; acc.y += pr[j2] * av.y;
                        acc.z += pr[j2] * av.z; acc.w += pr[j2] * av.w;
                    }
                    #pragma unroll
                    for (int j2 = 0; j2 < 7; ++j2) {
                        float4 bv = *(const float4*)(brow + j2 * 68 + cl4);
                        acc.x += pr[7 + j2] * bv.x; acc.y += pr[7 + j2] * bv.y;
                        acc.z += pr[7 + j2] * bv.z; acc.w += pr[7 + j2] * bv.w;
                    }
                    float* o = outn + (c0 + cl4) * 49 + hw;
                    o[0]   = acc.x;
                    o[49]  = acc.y;
                    o[98]  = acc.z;
                    o[147] = acc.w;
                }
            }
        }
        if (chunk < 3) __syncthreads();   // compute done before next overwrite
    }
}

extern "C" void kernel_launch(void* const* d_in, const int* in_sizes, int n_in,
                              void* d_out, int out_size, void* d_ws, size_t ws_size,
                              hipStream_t stream) {
    const float* qH = (const float*)d_in[0];
    const float* kH = (const float*)d_in[1];
    const float* vH = (const float*)d_in[2];
    const float* qW = (const float*)d_in[3];
    const float* kW = (const float*)d_in[4];
    const float* vW = (const float*)d_in[5];
    float* out = (float*)d_out;
    fused_axial<<<1024, 512, 0, stream>>>(qH, kH, vH, qW, kW, vW, out);
}

// Round 3
// 231.999 us; speedup vs baseline: 1.0705x; 1.0705x over previous
//
#include <hip/hip_runtime.h>

// Axial 7x7 attention, fused. N=512, GRID=7, Cq=64, Cv=512, B=3584.
// Round-3 = round-2 resubmission (bench infra failed; kernel never measured).
// Design:
//  - ALL LDS staging via __builtin_amdgcn_global_load_lds (no VGPR round trip ->
//    no register-staging spills, which killed round 1: WRITE_SIZE 182MB)
//  - k staged transposed kT[a][j][c] (gather source, linear LDS dest)
//  - v staged coalesced (256B/inst) into natural [w][c*7+j] layout, w-stride 452
//    (pad 4) -> PV ds_read_b128 conflict-free (banks spread 4*w), zero waste
//  - split-phase pipeline: compute vH-half | issue vH(c+1) | compute vW-half+store
//    | issue vW(c+1): every load batch has compute before its barrier vmcnt drain
//  - logits: wave = one (arr,a) group, lane=(b,j): q global reads 7 lines/inst
//  - grid 1024 (n, c-half), XCD-bijective swizzle, 30.4KB LDS, target 4 blocks/CU

#define NEGINF (-1e20f)

constexpr int QK_SLICE = 7 * 7 * 64;    // 3136 floats per n (q/k arrays)
constexpr int V_SLICE  = 7 * 512 * 7;   // 25088 floats per n (v arrays / out)

__device__ __forceinline__ void g2l4(const float* g, float* l) {
    __builtin_amdgcn_global_load_lds(
        (const __attribute__((address_space(1))) void*)g,
        (__attribute__((address_space(3))) void*)l, 4, 0, 0);
}

__global__ __launch_bounds__(512, 8) void fused_axial(
    const float* __restrict__ qH, const float* __restrict__ kH,
    const float* __restrict__ vH, const float* __restrict__ qW,
    const float* __restrict__ kW, const float* __restrict__ vW,
    float* __restrict__ out)
{
    // LDS (dwords): union U[6776]:
    //   k-phase: kTH = U+0 (3388, [a][j][c] strides 484/68), kTW = U+3388
    //   v-phase: As  = U+0 (3164, [w][452]: c_local*7+j flat, pad 4), Bs = U+3164
    // P = sm+6776: 49 rows x stride 17 (833).  Total 7609 dwords = 30436 B.
    __shared__ float sm[7609];
    float* U = sm;
    float* P = sm + 6776;

    const int bid  = blockIdx.x;
    const int work = (bid & 7) * 128 + (bid >> 3);   // bijective XCD swizzle
    const int n    = work >> 1;
    const int hf   = work & 1;                        // c-half: 0/1 -> 256 channels
    const int t    = threadIdx.x;
    const int lane = t & 63;
    const int wv   = t >> 6;                          // wave 0..7

    const float* qHn = qH + n * QK_SLICE;
    const float* kHn = kH + n * QK_SLICE;
    const float* qWn = qW + n * QK_SLICE;
    const float* kWn = kW + n * QK_SLICE;
    const float* vHn = vH + n * V_SLICE;
    const float* vWn = vW + n * V_SLICE;
    float* outn = out + n * V_SLICE;

    // ---- Phase K: gather-stage kT[arr][a][j][c] (98 insts across 8 waves) ----
    #pragma unroll
    for (int u = 0; u < 13; ++u) {
        const int r = wv + 8 * u;
        if (u < 12 || r < 98) {
            const int arr = r >= 49;
            const int wj  = r - 49 * arr;
            const int a   = (wj * 37) >> 8;           // wj/7
            const int j   = wj - 7 * a;
            const float* src = (arr ? kWn : kHn) + a * 448 + lane * 7 + j;
            float* dst = U + arr * 3388 + a * 484 + j * 68;   // + lane*4 implicit
            g2l4(src, dst);
        }
    }
    __syncthreads();   // kT staged (vmcnt drained by barrier)

    // ---- Phase L: logits. wave -> (arr,a) group, lane -> (b,j) ----
    {
        const int b = lane >> 3;
        const int j = lane & 7;
        auto logit_group = [&](int gi) {
            const int arr = gi >= 7;
            const int a   = gi - 7 * arr;
            if (b < 7 && j < 7) {
                const float* qrow = (arr ? qWn : qHn) + (a * 7 + b) * 64;
                const float* krow = U + arr * 3388 + a * 484 + j * 68;
                float e = 0.f;
                #pragma unroll
                for (int cc = 0; cc < 64; cc += 4) {
                    float4 qv = *(const float4*)(qrow + cc);
                    float4 kv = *(const float4*)(krow + cc);
                    e += qv.x * kv.x + qv.y * kv.y + qv.z * kv.z + qv.w * kv.w;
                }
                if (!arr) {
                    if (b == j) e = NEGINF;           // diagonal mask (h==j)
                    P[(b * 7 + a) * 17 + j] = e;      // logits[h=b, w=a, j]
                } else {
                    P[(a * 7 + b) * 17 + 7 + j] = e;  // logits[h=a, w=b, 7+y]
                }
            }
        };
        logit_group(wv);
        if (wv < 6) logit_group(wv + 8);
    }
    __syncthreads();   // logits done; kT region free

    // v-stage issuer: 49 coalesced insts (w 0..6 x part 0..6), 256B each
    const int c0base = hf * 256;
    auto issue_v = [&](float* dstb, const float* srcb, int c0) {
        const float* s0 = srcb + c0 * 7 + lane;
        #pragma unroll
        for (int u = 0; u < 7; ++u) {
            const int r = wv + 8 * u;
            if (u < 6 || r < 49) {
                const int w2   = (r * 37) >> 8;       // r/7
                const int part = r - 7 * w2;
                g2l4(s0 + w2 * 3584 + part * 64, dstb + w2 * 452 + part * 64);
            }
        }
    };

    float* As = U;
    float* Bs = U + 3164;

    // issue chunk-0 v loads; they fly while softmax runs
    issue_v(As, vHn, c0base);
    issue_v(Bs, vWn, c0base);

    // ---- Phase S: softmax over 14 per (h,w) ----
    if (t < 49) {
        float* row = P + t * 17;
        float l[14];
        float m = -3.4e38f;
        #pragma unroll
        for (int k = 0; k < 14; ++k) { l[k] = row[k]; m = fmaxf(m, l[k]); }
        float s = 0.f;
        #pragma unroll
        for (int k = 0; k < 14; ++k) { l[k] = __expf(l[k] - m); s += l[k]; }
        float inv = 1.f / s;
        #pragma unroll
        for (int k = 0; k < 14; ++k) row[k] = l[k] * inv;
    }
    __syncthreads();   // v chunk 0 landed; P final

    // ---- Phase PV ----
    const int g  = (t * 1339) >> 16;     // t/49
    const int hw = t - g * 49;
    const int h  = (hw * 37) >> 8;
    const int w  = hw - 7 * h;
    const bool active = (t < 490);

    float pr[14];
    if (active) {
        #pragma unroll
        for (int k = 0; k < 14; ++k) pr[k] = P[hw * 17 + k];
    }

    for (int chunk = 0; chunk < 4; ++chunk) {
        float ac[8] = {0.f, 0.f, 0.f, 0.f, 0.f, 0.f, 0.f, 0.f};

        // -- vH half: ac += pr[0..6] * As[w] --
        if (active) {
            const float* rowA = As + w * 452;
            #pragma unroll
            for (int it = 0; it < 2; ++it) {
                if (it == 0 || g < 6) {
                    const float* rr = rowA + (g + 10 * it) * 28;   // cl4*7
                    #pragma unroll
                    for (int q = 0; q < 7; ++q) {
                        float4 f = *(const float4*)(rr + 4 * q);
                        ac[it * 4 + (4 * q + 0) / 7] += pr[(4 * q + 0) % 7] * f.x;
                        ac[it * 4 + (4 * q + 1) / 7] += pr[(4 * q + 1) % 7] * f.y;
                        ac[it * 4 + (4 * q + 2) / 7] += pr[(4 * q + 2) % 7] * f.z;
                        ac[it * 4 + (4 * q + 3) / 7] += pr[(4 * q + 3) % 7] * f.w;
                    }
                }
            }
        }
        __syncthreads();                       // As reads done; As free
        if (chunk < 3) issue_v(As, vHn, c0base + (chunk + 1) * 64);

        // -- vW half + stores: ac += pr[7..13] * Bs[h] --
        if (active) {
            const float* rowB = Bs + h * 452;
            const int c0 = c0base + chunk * 64;
            #pragma unroll
            for (int it = 0; it < 2; ++it) {
                if (it == 0 || g < 6) {
                    const float* rr = rowB + (g + 10 * it) * 28;
                    #pragma unroll
                    for (int q = 0; q < 7; ++q) {
                        float4 f = *(const float4*)(rr + 4 * q);
                        ac[it * 4 + (4 * q + 0) / 7] += pr[7 + (4 * q + 0) % 7] * f.x;
                        ac[it * 4 + (4 * q + 1) / 7] += pr[7 + (4 * q + 1) % 7] * f.y;
                        ac[it * 4 + (4 * q + 2) / 7] += pr[7 + (4 * q + 2) % 7] * f.z;
                        ac[it * 4 + (4 * q + 3) / 7] += pr[7 + (4 * q + 3) % 7] * f.w;
                    }
                    const int cl4 = (g + 10 * it) * 4;
                    float* o = outn + (c0 + cl4) * 49 + hw;
                    o[0]   = ac[it * 4 + 0];
                    o[49]  = ac[it * 4 + 1];
                    o[98]  = ac[it * 4 + 2];
                    o[147] = ac[it * 4 + 3];
                }
            }
        }
        if (chunk < 3) {
            __syncthreads();                   // Bs reads done; drains As(c+1) issue
            issue_v(Bs, vWn, c0base + (chunk + 1) * 64);
            // iteration c+1's As-compute runs while Bs(c+1) flies; the mid-loop
            // barrier of c+1 drains it before Bs is read.
        }
    }
}

extern "C" void kernel_launch(void* const* d_in, const int* in_sizes, int n_in,
                              void* d_out, int out_size, void* d_ws, size_t ws_size,
                              hipStream_t stream) {
    const float* qH = (const float*)d_in[0];
    const float* kH = (const float*)d_in[1];
    const float* vH = (const float*)d_in[2];
    const float* qW = (const float*)d_in[3];
    const float* kW = (const float*)d_in[4];
    const float* vW = (const float*)d_in[5];
    float* out = (float*)d_out;
    fused_axial<<<1024, 512, 0, stream>>>(qH, kH, vH, qW, kW, vW, out);
}

// Round 4
// 178.522 us; speedup vs baseline: 1.3911x; 1.2996x over previous
//
#include <hip/hip_runtime.h>

// Axial 7x7 attention, fused. N=512, GRID=7, Cq=64, Cv=512, B=3584.
// Round-4:
//  - grid 512, one n per block (round-0's proven minimal-traffic structure)
//  - __launch_bounds__(512,4): 128-VGPR budget -> no scratch spills (rounds 1/3
//    had a 64-VGPR cap; spill traffic inflated WRITE 59->140MB and killed perf)
//  - all staging via global_load_lds; k transposed kT[a][j][c]; v coalesced
//    into [w][cl*7+j] (stride 452) -> conflict-free ds_read_b128, zero waste
//  - 8 chunks x 64 channels, DOUBLE-buffered A/B v-tiles: chunk c+2 issued at
//    end of chunk c, in flight across all of chunk c+1's compute, drained by
//    its trailing barrier. One barrier per chunk; 50KB/CU in flight >= BW*lat.
//  - LDS: A0|B0|union{A1,B1 / kTH,kTW}|P = 55.7KB -> 2 blocks/CU (grid-matched)

#define NEGINF (-1e20f)

constexpr int QK_SLICE = 7 * 7 * 64;    // 3136 floats per n (q/k arrays)
constexpr int V_SLICE  = 7 * 512 * 7;   // 25088 floats per n (v arrays / out)

__device__ __forceinline__ void g2l4(const float* g, float* l) {
    __builtin_amdgcn_global_load_lds(
        (const __attribute__((address_space(1))) void*)g,
        (__attribute__((address_space(3))) void*)l, 4, 0, 0);
}

__global__ __launch_bounds__(512, 4) void fused_axial(
    const float* __restrict__ qH, const float* __restrict__ kH,
    const float* __restrict__ vH, const float* __restrict__ qW,
    const float* __restrict__ kW, const float* __restrict__ vW,
    float* __restrict__ out)
{
    // LDS (dwords):
    //   A0: 0..3163        (v-tile, [7][452])
    //   B0: 3164..6327
    //   U1: 6328..13103    union: {A1 = U1, B1 = U1+3164}  OR  {kTH = U1 (3388,
    //       [a][j][c] strides 484/68), kTW = U1+3388} -- kT dies after logits
    //   P : 13104..13936   (49 rows x stride 17)
    // total 13937 dwords = 55748 B -> 2 blocks/CU.
    __shared__ float sm[13937];
    float* A0 = sm;
    float* B0 = sm + 3164;
    float* U1 = sm + 6328;
    float* P  = sm + 13104;

    const int n    = blockIdx.x;
    const int t    = threadIdx.x;
    const int lane = t & 63;
    const int wv   = t >> 6;                          // wave 0..7

    const float* qHn = qH + n * QK_SLICE;
    const float* kHn = kH + n * QK_SLICE;
    const float* qWn = qW + n * QK_SLICE;
    const float* kWn = kW + n * QK_SLICE;
    const float* vHn = vH + n * V_SLICE;
    const float* vWn = vW + n * V_SLICE;
    float* outn = out + n * V_SLICE;

    // ---- Phase K: gather-stage kT[arr][a][j][c] into U1 (98 insts, 8 waves) ----
    #pragma unroll
    for (int u = 0; u < 13; ++u) {
        const int r = wv + 8 * u;
        if (u < 12 || r < 98) {
            const int arr = r >= 49;
            const int wj  = r - 49 * arr;
            const int a   = (wj * 37) >> 8;           // wj/7
            const int j   = wj - 7 * a;
            const float* src = (arr ? kWn : kHn) + a * 448 + lane * 7 + j;
            float* dst = U1 + arr * 3388 + a * 484 + j * 68;  // + lane*4 implicit
            g2l4(src, dst);
        }
    }
    __syncthreads();   // kT staged (barrier drains vmcnt)

    // ---- Phase L: logits. wave -> (arr,a) group, lane -> (b,j) ----
    {
        const int b = lane >> 3;
        const int j = lane & 7;
        auto logit_group = [&](int gi) {
            const int arr = gi >= 7;
            const int a   = gi - 7 * arr;
            if (b < 7 && j < 7) {
                const float* qrow = (arr ? qWn : qHn) + (a * 7 + b) * 64;
                const float* krow = U1 + arr * 3388 + a * 484 + j * 68;
                float e = 0.f;
                #pragma unroll
                for (int cc = 0; cc < 64; cc += 4) {
                    float4 qv = *(const float4*)(qrow + cc);
                    float4 kv = *(const float4*)(krow + cc);
                    e += qv.x * kv.x + qv.y * kv.y + qv.z * kv.z + qv.w * kv.w;
                }
                if (!arr) {
                    if (b == j) e = NEGINF;           // diagonal mask (h==j)
                    P[(b * 7 + a) * 17 + j] = e;      // logits[h=b, w=a, j]
                } else {
                    P[(a * 7 + b) * 17 + 7 + j] = e;  // logits[h=a, w=b, 7+y]
                }
            }
        };
        logit_group(wv);
        if (wv < 6) logit_group(wv + 8);
    }
    __syncthreads();   // logits in P; kT region (U1) now free for A1/B1

    // v-stage issuer: 49 coalesced insts (w2 0..6 x part 0..6), 256B each
    auto issue_v = [&](float* dstb, const float* srcb, int c0) {
        const float* s0 = srcb + c0 * 7 + lane;
        #pragma unroll
        for (int u = 0; u < 7; ++u) {
            const int r = wv + 8 * u;
            if (u < 6 || r < 49) {
                const int w2   = (r * 37) >> 8;       // r/7
                const int part = r - 7 * w2;
                g2l4(s0 + w2 * 3584 + part * 64, dstb + w2 * 452 + part * 64);
            }
        }
    };

    // issue chunks 0 and 1 (4 batches, ~50KB in flight); they fly under softmax
    issue_v(A0,        vHn, 0);
    issue_v(B0,        vWn, 0);
    issue_v(U1,        vHn, 64);   // A1
    issue_v(U1 + 3164, vWn, 64);   // B1

    // ---- Phase S: softmax over 14 per (h,w) ----
    if (t < 49) {
        float* row = P + t * 17;
        float l[14];
        float m = -3.4e38f;
        #pragma unroll
        for (int k = 0; k < 14; ++k) { l[k] = row[k]; m = fmaxf(m, l[k]); }
        float s = 0.f;
        #pragma unroll
        for (int k = 0; k < 14; ++k) { l[k] = __expf(l[k] - m); s += l[k]; }
        float inv = 1.f / s;
        #pragma unroll
        for (int k = 0; k < 14; ++k) row[k] = l[k] * inv;
    }
    __syncthreads();   // chunks 0/1 landed; P final

    // ---- Phase PV: 8 chunks x 64 channels, double-buffered ----
    const int g  = (t * 1339) >> 16;     // t/49
    const int hw = t - g * 49;
    const int h  = (hw * 37) >> 8;
    const int w  = hw - 7 * h;
    const bool active = (t < 490);

    float pr[14];
    if (active) {
        #pragma unroll
        for (int k = 0; k < 14; ++k) pr[k] = P[hw * 17 + k];
    }

    for (int chunk = 0; chunk < 8; ++chunk) {
        float* As = (chunk & 1) ? U1        : A0;
        float* Bs = (chunk & 1) ? U1 + 3164 : B0;
        const int c0 = chunk * 64;

        if (active) {
            const float* rowA = As + w * 452;
            const float* rowB = Bs + h * 452;
            #pragma unroll
            for (int it = 0; it < 2; ++it) {
                if (it == 0 || g < 6) {
                    const int quad = g + 10 * it;          // 0..15
                    const float* ra = rowA + quad * 28;
                    const float* rb = rowB + quad * 28;
                    float ac[4] = {0.f, 0.f, 0.f, 0.f};
                    #pragma unroll
                    for (int q = 0; q < 7; ++q) {
                        float4 f = *(const float4*)(ra + 4 * q);
                        ac[(4 * q + 0) / 7] += pr[(4 * q + 0) % 7] * f.x;
                        ac[(4 * q + 1) / 7] += pr[(4 * q + 1) % 7] * f.y;
                        ac[(4 * q + 2) / 7] += pr[(4 * q + 2) % 7] * f.z;
                        ac[(4 * q + 3) / 7] += pr[(4 * q + 3) % 7] * f.w;
                    }
                    #pragma unroll
                    for (int q = 0; q < 7; ++q) {
                        float4 f = *(const float4*)(rb + 4 * q);
                        ac[(4 * q + 0) / 7] += pr[7 + (4 * q + 0) % 7] * f.x;
                        ac[(4 * q + 1) / 7] += pr[7 + (4 * q + 1) % 7] * f.y;
                        ac[(4 * q + 2) / 7] += pr[7 + (4 * q + 2) % 7] * f.z;
                        ac[(4 * q + 3) / 7] += pr[7 + (4 * q + 3) % 7] * f.w;
                    }
                    float* o = outn + (c0 + quad * 4) * 49 + hw;
                    o[0]   = ac[0];
                    o[49]  = ac[1];
                    o[98]  = ac[2];
                    o[147] = ac[3];
                }
            }
        }
        __syncthreads();   // reads of current buffers done; drains chunk+1 data
        if (chunk < 6) {   // issue chunk+2 into the buffers just freed
            issue_v(As, vHn, (chunk + 2) * 64);
            issue_v(Bs, vWn, (chunk + 2) * 64);
        }
    }
}

extern "C" void kernel_launch(void* const* d_in, const int* in_sizes, int n_in,
                              void* d_out, int out_size, void* d_ws, size_t ws_size,
                              hipStream_t stream) {
    const float* qH = (const float*)d_in[0];
    const float* kH = (const float*)d_in[1];
    const float* vH = (const float*)d_in[2];
    const float* qW = (const float*)d_in[3];
    const float* kW = (const float*)d_in[4];
    const float* vW = (const float*)d_in[5];
    float* out = (float*)d_out;
    fused_axial<<<512, 512, 0, stream>>>(qH, kH, vH, qW, kW, vW, out);
}